// Round 8
// baseline (422.321 us; speedup 1.0000x reference)
//
#include <hip/hip_runtime.h>
#include <hip/hip_cooperative_groups.h>
#include <math.h>

namespace cg = cooperative_groups;

// Tropical bottleneck network, fp32 — single persistent cooperative kernel.
// 256 blocks x 512 threads (LDS 80KB -> 1 block/CU), 10 grid.sync()s.
// Activations chunked-transposed [K/4][1024][4]; lane = batch b.
// Per stage: W staged to LDS (broadcast ds_read_b128), BT=4 batch-tiles/wave,
// 2 row-waves x 4-way K-split, LDS partial combine. RH = rows per wave.

#define BALL 1024

struct Plan {
    const float *x, *w11, *w12, *b12, *w21, *w22, *b22, *w31, *w32, *b32,
                *w41, *w42, *b42, *sw1, *sw2, *sb2, *scw1, *scw2, *scb2;
    float *Xc, *M, *A, *SC0, *SCout, *T, *T2, *Zf, *O4, *out;
};

__device__ __forceinline__ float rdop(float a, float b, int ismax) {
    return ismax ? fmaxf(a, b) : fminf(a, b);
}

#define RD(x, y) (ISMAX ? fmaxf((x), (y)) : fminf((x), (y)))

// one semiring stage slice: block idx -> (bcol of 256 b, row-group of 2*RH rows)
template<int ISMAX, int K, int RH>
__device__ void runS(const float* __restrict__ X, const float* __restrict__ W,
                     const float* __restrict__ bias, const float* __restrict__ E1,
                     const float* __restrict__ E2, float* __restrict__ Y,
                     int idx, float* __restrict__ lds)
{
    const int tid  = threadIdx.x;
    const int lane = tid & 63;
    const int wv   = tid >> 6;       // 0..7
    const int rw   = wv & 1;         // row-wave
    const int q    = wv >> 1;        // K-quarter
    const int b0   = (idx & 3) * 256;
    const int i0   = (idx >> 2) * (2 * RH);
    const int r0   = rw * RH;

    float4* Wl4 = (float4*)lds;                    // 2*RH*K floats
    float*  part = lds + 2 * RH * K;               // [3][2*RH][256]

    // stage W[2*RH rows][K] into LDS, coalesced float4
    const float4* Wg = (const float4*)(W + (size_t)i0 * K);
    constexpr int NF4 = RH * K / 2;
#pragma unroll
    for (int t = tid; t < NF4; t += 512) Wl4[t] = Wg[t];
    __syncthreads();

    constexpr int CQ = K / 16;                     // chunks per K-quarter
    const int kcB = q * CQ;
    const float4* Xb = (const float4*)X + b0 + lane;
    const float4* Wr = Wl4 + r0 * (K / 4);

    float acc[RH][4];
    {   // peel first chunk (no +-INF init)
        float4 xv[4];
#pragma unroll
        for (int bt = 0; bt < 4; ++bt) xv[bt] = Xb[(size_t)kcB * BALL + bt * 64];
#pragma unroll
        for (int r = 0; r < RH; ++r) {
            float4 w = Wr[r * (K / 4) + kcB];
#pragma unroll
            for (int bt = 0; bt < 4; ++bt)
                acc[r][bt] = RD(RD(xv[bt].x + w.x, xv[bt].y + w.y),
                                RD(xv[bt].z + w.z, xv[bt].w + w.w));
        }
    }
#pragma unroll 2
    for (int kc = kcB + 1; kc < kcB + CQ; ++kc) {
        float4 xv[4];
#pragma unroll
        for (int bt = 0; bt < 4; ++bt) xv[bt] = Xb[(size_t)kc * BALL + bt * 64];
#pragma unroll
        for (int r = 0; r < RH; ++r) {
            float4 w = Wr[r * (K / 4) + kc];
#pragma unroll
            for (int bt = 0; bt < 4; ++bt)   // fuses to v_min3/v_max3 pairs
                acc[r][bt] = RD(RD(RD(RD(xv[bt].x + w.x, xv[bt].y + w.y),
                                      xv[bt].z + w.z), xv[bt].w + w.w), acc[r][bt]);
        }
    }

    // combine K-quarters via LDS
    if (q) {
#pragma unroll
        for (int r = 0; r < RH; ++r)
#pragma unroll
            for (int bt = 0; bt < 4; ++bt)
                part[((q - 1) * (2 * RH) + r0 + r) * 256 + bt * 64 + lane] = acc[r][bt];
    }
    __syncthreads();
    if (q == 0) {
#pragma unroll
        for (int qq = 0; qq < 3; ++qq)
#pragma unroll
            for (int r = 0; r < RH; ++r)
#pragma unroll
                for (int bt = 0; bt < 4; ++bt)
                    acc[r][bt] = RD(acc[r][bt],
                                    part[(qq * (2 * RH) + r0 + r) * 256 + bt * 64 + lane]);

        if constexpr (RH >= 4) {
            const int c0 = (i0 + r0) >> 2;
#pragma unroll
            for (int cc = 0; cc < RH / 4; ++cc) {
                float4 bb;
                if (ISMAX) bb = *(const float4*)(bias + i0 + r0 + cc * 4);
#pragma unroll
                for (int bt = 0; bt < 4; ++bt) {
                    const int b = b0 + bt * 64 + lane;
                    float4 v = make_float4(acc[cc * 4 + 0][bt], acc[cc * 4 + 1][bt],
                                           acc[cc * 4 + 2][bt], acc[cc * 4 + 3][bt]);
                    if (ISMAX) { v.x += bb.x; v.y += bb.y; v.z += bb.z; v.w += bb.w; }
                    if (E1) {
                        float4 e = ((const float4*)E1)[(size_t)(c0 + cc) * BALL + b];
                        v.x = fminf(v.x, e.x); v.y = fminf(v.y, e.y);
                        v.z = fminf(v.z, e.z); v.w = fminf(v.w, e.w);
                    }
                    if (E2) {
                        float4 e = ((const float4*)E2)[(size_t)(c0 + cc) * BALL + b];
                        v.x = fmaxf(v.x, e.x); v.y = fmaxf(v.y, e.y);
                        v.z = fmaxf(v.z, e.z); v.w = fmaxf(v.w, e.w);
                    }
                    ((float4*)Y)[(size_t)(c0 + cc) * BALL + b] = v;
                }
            }
        } else {   // RH == 2: store float2 (half a chunk per wave)
            const int c0 = i0 >> 2;          // i0 multiple of 4; r0 in {0,2}
            float2 bb;
            if (ISMAX) bb = *(const float2*)(bias + i0 + r0);
#pragma unroll
            for (int bt = 0; bt < 4; ++bt) {
                const int b = b0 + bt * 64 + lane;
                const size_t f2i = (((size_t)c0 * BALL + b) << 1) | (r0 >> 1);
                float2 v = make_float2(acc[0][bt], acc[1][bt]);
                if (ISMAX) { v.x += bb.x; v.y += bb.y; }
                if (E1) {
                    float2 e = ((const float2*)E1)[f2i];
                    v.x = fminf(v.x, e.x); v.y = fminf(v.y, e.y);
                }
                if (E2) {
                    float2 e = ((const float2*)E2)[f2i];
                    v.x = fmaxf(v.x, e.x); v.y = fmaxf(v.y, e.y);
                }
                ((float2*)Y)[f2i] = v;
            }
        }
    }
}
#undef RD

// x [1024][256] -> Xc chunked [64][1024][4]; 64 jobs of (64 b x 64 k), 512 thr
__device__ void t_in_dev(const float* __restrict__ x, float* __restrict__ Xc,
                         int job, float* __restrict__ lds)
{
    float (*s)[65] = (float (*)[65])lds;
    const int lane = threadIdx.x & 63;
    const int wv   = threadIdx.x >> 6;
    const int b0   = (job & 15) * 64;
    const int k0   = (job >> 4) * 64;
#pragma unroll
    for (int r = wv; r < 64; r += 8)
        s[r][lane] = x[(size_t)(b0 + r) * 256 + k0 + lane];
    __syncthreads();
    float4* X4 = (float4*)Xc;
#pragma unroll
    for (int cc = 0; cc < 2; ++cc) {
        int c = wv * 2 + cc;
        float4 v = make_float4(s[lane][c * 4 + 0], s[lane][c * 4 + 1],
                               s[lane][c * 4 + 2], s[lane][c * 4 + 3]);
        X4[(size_t)(k0 / 4 + c) * BALL + b0 + lane] = v;
    }
}

// Zc chunked [128][1024][4] -> out [1024][512]; 128 jobs of (64 i x 64 b)
__device__ void t_out_dev(const float* __restrict__ Zc, float* __restrict__ out,
                          int job, float* __restrict__ lds)
{
    float (*s)[65] = (float (*)[65])lds;
    const int lane = threadIdx.x & 63;
    const int wv   = threadIdx.x >> 6;
    const int i0   = (job & 7) * 64;
    const int b0   = (job >> 3) * 64;
    const float4* Z4 = (const float4*)Zc;
#pragma unroll
    for (int cc = 0; cc < 2; ++cc) {
        int c = wv * 2 + cc;
        float4 v = Z4[(size_t)(i0 / 4 + c) * BALL + b0 + lane];
        s[lane][c * 4 + 0] = v.x; s[lane][c * 4 + 1] = v.y;
        s[lane][c * 4 + 2] = v.z; s[lane][c * 4 + 3] = v.w;
    }
    __syncthreads();
#pragma unroll
    for (int r = wv; r < 64; r += 8)
        out[(size_t)(b0 + r) * 512 + i0 + lane] = s[r][lane];
}

__global__ __launch_bounds__(512, 2) void netk(Plan p)
{
    __shared__ __align__(16) float lds[20480];   // 80 KB: max(Wl 2*8*512, +part 3*16*256)
    cg::grid_group g = cg::this_grid();
    const int bid = blockIdx.x;

    // P0: transpose x -> Xc
    if (bid < 64) t_in_dev(p.x, p.Xc, bid, lds);
    g.sync();
    // P1: layer1 min-plus || bottleneck-sc min-plus
    if (bid < 128) runS<0, 256, 4>(p.Xc, p.w11, nullptr, nullptr, nullptr, p.M, bid, lds);
    else           runS<0, 256, 8>(p.Xc, p.scw1, nullptr, nullptr, nullptr, p.SC0, bid - 128, lds);
    g.sync();
    // P2: layer1 max-plus (min x) || bottleneck-sc max-plus
    if (bid < 128) runS<1, 256, 4>(p.M, p.w12, p.b12, p.Xc, nullptr, p.A, bid, lds);
    else           runS<1, 512, 8>(p.SC0, p.scw2, p.scb2, nullptr, nullptr, p.SCout, bid - 128, lds);
    g.sync();
    // P3-P6: layers 2,3
    runS<0, 256, 2>(p.A, p.w21, nullptr, nullptr, nullptr, p.M, bid, lds);  g.sync();
    runS<1, 256, 2>(p.M, p.w22, p.b22, p.A, nullptr, p.Xc, bid, lds);       g.sync(); // X2 = Xc
    runS<0, 256, 2>(p.Xc, p.w31, nullptr, nullptr, nullptr, p.M, bid, lds); g.sync();
    runS<1, 256, 2>(p.M, p.w32, p.b32, p.Xc, nullptr, p.A, bid, lds);       g.sync(); // A = x3
    // P7: layer4 main min-plus || shortcut min-plus
    if (bid < 128) runS<0, 256, 8>(p.A, p.w41, nullptr, nullptr, nullptr, p.T, bid, lds);
    else           runS<0, 256, 8>(p.A, p.sw1, nullptr, nullptr, nullptr, p.T2, bid - 128, lds);
    g.sync();
    // P8: layer4 main max-plus -> O4 (staged in d_out)
    runS<1, 512, 4>(p.T, p.w42, p.b42, nullptr, nullptr, p.O4, bid, lds);   g.sync();
    // P9: layer4 shortcut max-plus, min O4, max SCout -> Zf
    runS<1, 512, 4>(p.T2, p.sw2, p.sb2, p.O4, p.SCout, p.Zf, bid, lds);     g.sync();
    // P10: un-transpose
    if (bid < 128) t_out_dev(p.Zf, p.out, bid, lds);
}

extern "C" void kernel_launch(void* const* d_in, const int* in_sizes, int n_in,
                              void* d_out, int out_size, void* d_ws, size_t ws_size,
                              hipStream_t stream) {
    (void)in_sizes; (void)n_in; (void)ws_size; (void)out_size;
    float* out = (float*)d_out;
    float* ws  = (float*)d_ws;

    Plan p;
    p.x    = (const float*)d_in[0];
    p.w11  = (const float*)d_in[1];  p.w12 = (const float*)d_in[2];  p.b12 = (const float*)d_in[3];
    p.w21  = (const float*)d_in[4];  p.w22 = (const float*)d_in[5];  p.b22 = (const float*)d_in[6];
    p.w31  = (const float*)d_in[7];  p.w32 = (const float*)d_in[8];  p.b32 = (const float*)d_in[9];
    p.w41  = (const float*)d_in[10]; p.w42 = (const float*)d_in[11]; p.b42 = (const float*)d_in[12];
    p.sw1  = (const float*)d_in[13]; p.sw2 = (const float*)d_in[14]; p.sb2 = (const float*)d_in[15];
    p.scw1 = (const float*)d_in[16]; p.scw2 = (const float*)d_in[17]; p.scb2 = (const float*)d_in[18];

    // workspace (floats), 7.0 MB peak; lifetime-disjoint aliases as in R5/R7:
    p.Xc    = ws;             // 1 MB; later reused as X2 (layer-2/3 activations)
    p.M     = ws + 262144;    // 1 MB
    p.A     = ws + 524288;    // 1 MB
    p.SC0   = ws + 786432;    // 2 MB
    p.SCout = ws + 1310720;   // 2 MB
    p.T     = p.SC0;          // layer-4 main pre-act (SC0 dead after P2)
    p.T2    = ws;             // layer-4 shortcut pre-act over [Xc,M] (dead after P6)
    p.Zf    = p.SC0;          // final chunked result (T dead after P8)
    p.O4    = out;            // d_out doubles as chunked scratch, dead before P10
    p.out   = out;

    void* args[] = { &p };
    hipLaunchCooperativeKernel((void*)netk, dim3(256), dim3(512), args, 0, stream);
}

// Round 10
// 122.026 us; speedup vs baseline: 3.4609x; 3.4609x over previous
//
#include <hip/hip_runtime.h>
#include <math.h>

// Tropical bottleneck network — packed-f16 compute on the R5-proven structure.
// Uses clang-native _Float16 ext-vectors (no hip_fp16.h) -> v_pk_*_f16.
// Activations chunked-transposed [K/8][1024][8] halfs; lane = batch b; each
// 16B chunk = 8 k-values. W converted to f16 once per call, staged to LDS per
// block, read broadcast (ds_read_b128 = 8 k).
// 512 threads = 8 waves = 2 row-waves (8 rows) x 4 K-quarters, LDS combine.

#define BALL 1024

typedef _Float16 h2 __attribute__((ext_vector_type(2)));
typedef _Float16 h4 __attribute__((ext_vector_type(4)));
typedef _Float16 h8 __attribute__((ext_vector_type(8)));

template<int M> __device__ __forceinline__ h8 rd8(h8 a, h8 b) {
    if constexpr (M) return __builtin_elementwise_max(a, b);
    else             return __builtin_elementwise_min(a, b);
}
template<int M> __device__ __forceinline__ h4 rd4(h4 a, h4 b) {
    if constexpr (M) return __builtin_elementwise_max(a, b);
    else             return __builtin_elementwise_min(a, b);
}
template<int M> __device__ __forceinline__ h2 rd2v(h2 a, h2 b) {
    if constexpr (M) return __builtin_elementwise_max(a, b);
    else             return __builtin_elementwise_min(a, b);
}
template<int M> __device__ __forceinline__ _Float16 rd1(_Float16 a, _Float16 b) {
    if constexpr (M) return a > b ? a : b;
    else             return a < b ? a : b;
}
template<int M> __device__ __forceinline__ h2 red82(h8 v) {
    h4 lo = __builtin_shufflevector(v, v, 0, 1, 2, 3);
    h4 hi = __builtin_shufflevector(v, v, 4, 5, 6, 7);
    h4 m  = rd4<M>(lo, hi);
    h2 a  = __builtin_shufflevector(m, m, 0, 1);
    h2 b  = __builtin_shufflevector(m, m, 2, 3);
    return rd2v<M>(a, b);
}

struct JobH {
    const h8*       X;    // chunked [K/8][1024]
    const _Float16* W;    // [rows][K] row-major
    const _Float16* bias; // [rows] (max stages)
    const h8*       E1;   // chunked min-combine or nullptr
    const h8*       E2;   // chunked max-combine or nullptr
    h8*             Y;    // chunked [rows/8][1024]
};

// accumulate 8 rows over chunks [kcB, kcB + K/32); acc stays 8-wide (k-slots)
template<int ISMAX, int K>
__device__ __forceinline__ void accumH(
    const h8* __restrict__ Xb, const h8* __restrict__ Wr,
    int kcB, h8 (&acc)[8])
{
    constexpr int CQ = K / 32;
    {   // peel first chunk: init = x + w (no +-INF)
        h8 xv = Xb[(size_t)kcB * BALL];
#pragma unroll
        for (int r = 0; r < 8; ++r) acc[r] = xv + Wr[r * (K / 8) + kcB];
    }
#pragma unroll 2
    for (int kc = kcB + 1; kc < kcB + CQ; ++kc) {
        h8 xv = Xb[(size_t)kc * BALL];
#pragma unroll
        for (int r = 0; r < 8; ++r)
            acc[r] = rd8<ISMAX>(acc[r], xv + Wr[r * (K / 8) + kc]);
    }
}

template<int ISMAX, int K>
__device__ __forceinline__ void run_jobH(
    const JobH j, int by, h8* __restrict__ Wl,
    h2 (* __restrict__ part)[16][64])
{
    const int tid  = threadIdx.x;
    const int lane = tid & 63;
    const int wv   = tid >> 6;
    const int rw   = wv & 1;
    const int q    = wv >> 1;
    const int b    = blockIdx.x * 64 + lane;
    const int i0   = by * 16;
    const int r0   = rw * 8;

    // stage W[16 rows][K halfs] into LDS, coalesced 16B
    const h8* Wg = (const h8*)(j.W + (size_t)i0 * K);
    constexpr int N8 = 2 * K;            // h8 count
#pragma unroll
    for (int t = tid; t < N8; t += 512) Wl[t] = Wg[t];
    __syncthreads();

    h8 acc[8];
    accumH<ISMAX, K>(j.X + b, Wl + (size_t)r0 * (K / 8), q * (K / 32), acc);

    if (q) {
#pragma unroll
        for (int r = 0; r < 8; ++r)
            part[q - 1][r0 + r][lane] = red82<ISMAX>(acc[r]);
    }
    __syncthreads();
    if (q == 0) {
        _Float16 v8[8];
#pragma unroll
        for (int r = 0; r < 8; ++r) {
            h2 m = red82<ISMAX>(acc[r]);
#pragma unroll
            for (int qq = 0; qq < 3; ++qq)
                m = rd2v<ISMAX>(m, part[qq][r0 + r][lane]);
            v8[r] = rd1<ISMAX>(m[0], m[1]);
        }
        h8 o;
#pragma unroll
        for (int jj = 0; jj < 8; ++jj) o[jj] = v8[jj];

        const int c0 = (i0 + r0) >> 3;
        if (ISMAX) o = o + *(const h8*)(j.bias + i0 + r0);
        if (j.E1)  o = __builtin_elementwise_min(o, j.E1[(size_t)c0 * BALL + b]);
        if (j.E2)  o = __builtin_elementwise_max(o, j.E2[(size_t)c0 * BALL + b]);
        j.Y[(size_t)c0 * BALL + b] = o;
    }
}

template<int ISMAX, int KA, int KB>
__global__ __launch_bounds__(512) void tsemi(JobH ja, JobH jb, int nbyA)
{
    constexpr int KM = (KA > KB) ? KA : KB;
    __shared__ __align__(16) h8 Wl[2 * KM];      // 16 rows x K halfs
    __shared__ h2 part[3][16][64];
    const int by = blockIdx.y;
    if (by < nbyA) run_jobH<ISMAX, KA>(ja, by, Wl, part);
    else           run_jobH<ISMAX, KB>(jb, by - nbyA, Wl, part);
}

// weight/bias f32 -> f16 conversion: 18 segments
struct CvtP {
    const float* s[18];
    _Float16*    d[18];
    int          n[18];
};
__global__ __launch_bounds__(256) void cvtk(CvtP p)
{
    const int seg = blockIdx.y;
    const float2* s2 = (const float2*)p.s[seg];
    h2*           d2 = (h2*)p.d[seg];
    const int n2 = p.n[seg] >> 1;
    for (int i = blockIdx.x * 256 + threadIdx.x; i < n2; i += gridDim.x * 256) {
        float2 v = s2[i];
        h2 o; o[0] = (_Float16)v.x; o[1] = (_Float16)v.y;
        d2[i] = o;
    }
}

// x f32 [1024][256] -> Xc f16 chunked [32][1024][8]
__global__ __launch_bounds__(256) void t_in(const float* __restrict__ x,
                                            h8* __restrict__ Xc)
{
    __shared__ float s[64][65];
    const int lane = threadIdx.x & 63;
    const int ty   = threadIdx.x >> 6;
    const int b0   = blockIdx.x * 64;
    const int k0   = blockIdx.y * 64;
#pragma unroll
    for (int r = ty; r < 64; r += 4)
        s[r][lane] = x[(size_t)(b0 + r) * 256 + k0 + lane];
    __syncthreads();
#pragma unroll
    for (int cc = 0; cc < 2; ++cc) {
        int c = ty * 2 + cc;            // chunk within tile, 0..7
        h8 v;
#pragma unroll
        for (int jj = 0; jj < 8; ++jj) v[jj] = (_Float16)s[lane][c * 8 + jj];
        Xc[(size_t)(k0 / 8 + c) * BALL + b0 + lane] = v;
    }
}

// Zf f16 chunked [64][1024][8] -> out f32 [1024][512]
__global__ __launch_bounds__(256) void t_out(const h8* __restrict__ Zc,
                                             float* __restrict__ out)
{
    __shared__ float s[64][65];
    const int lane = threadIdx.x & 63;
    const int ty   = threadIdx.x >> 6;
    const int i0   = blockIdx.x * 64;
    const int b0   = blockIdx.y * 64;
#pragma unroll
    for (int cc = 0; cc < 2; ++cc) {
        int c = ty * 2 + cc;            // row-chunk within tile, 0..7
        h8 v = Zc[(size_t)(i0 / 8 + c) * BALL + b0 + lane];
#pragma unroll
        for (int jj = 0; jj < 8; ++jj) s[lane][c * 8 + jj] = (float)v[jj];
    }
    __syncthreads();
#pragma unroll
    for (int r = ty; r < 64; r += 4)
        out[(size_t)(b0 + r) * 512 + i0 + lane] = s[r][lane];
}

extern "C" void kernel_launch(void* const* d_in, const int* in_sizes, int n_in,
                              void* d_out, int out_size, void* d_ws, size_t ws_size,
                              hipStream_t stream) {
    (void)in_sizes; (void)n_in; (void)ws_size; (void)out_size;
    const float* fin[19];
    for (int i = 0; i < 19; ++i) fin[i] = (const float*)d_in[i];
    const float* x = fin[0];

    float*     out = (float*)d_out;
    _Float16*  hw  = (_Float16*)d_ws;

    // half-unit workspace layout (~6.76 MB < 7.0 MB proven):
    _Float16* hXc    = hw;                 // 262144 halfs (x chunked; X2 alias)
    _Float16* hM     = hw + 262144;
    _Float16* hA     = hw + 524288;
    _Float16* hSC0   = hw + 786432;        // 524288 halfs
    _Float16* hSCout = hw + 1310720;       // 524288 halfs
    _Float16* hW     = hw + 1835008;       // converted weights+biases
    // lifetime-disjoint aliases:
    _Float16* hX2 = hXc;                   // layer-2/3 activations
    _Float16* hT  = hSC0;                  // layer-4 main pre-act
    _Float16* hT2 = hXc;                   // layer-4 shortcut pre-act (over Xc+M)
    _Float16* hZf = hSC0;                  // final chunked result
    _Float16* hO4 = (_Float16*)d_out;      // d_out doubles as f16 chunked scratch

    // converted-weight offsets (halfs)
    _Float16* w11  = hW;            _Float16* w12  = hW + 65536;
    _Float16* w21  = hW + 131072;   _Float16* w22  = hW + 196608;
    _Float16* w31  = hW + 262144;   _Float16* w32  = hW + 327680;
    _Float16* w41  = hW + 393216;   _Float16* w42  = hW + 524288;
    _Float16* sw1  = hW + 786432;   _Float16* sw2  = hW + 917504;
    _Float16* scw1 = hW + 1179648;  _Float16* scw2 = hW + 1441792;
    _Float16* b12  = hW + 1703936;  _Float16* b22  = hW + 1704192;
    _Float16* b32  = hW + 1704448;  _Float16* b42  = hW + 1704704;
    _Float16* sb2  = hW + 1705216;  _Float16* scb2 = hW + 1705728;

    CvtP cp;
    const int srcIdx[18] = {1,2,4,5,7,8, 10,11,13,14,16,17, 3,6,9,12,15,18};
    _Float16* dsts[18]   = {w11,w12,w21,w22,w31,w32, w41,w42,sw1,sw2,scw1,scw2,
                            b12,b22,b32,b42,sb2,scb2};
    const int ns[18]     = {65536,65536,65536,65536,65536,65536,
                            131072,262144,131072,262144,131072,262144,
                            256,256,256,512,512,512};
    for (int i = 0; i < 18; ++i) { cp.s[i] = fin[srcIdx[i]]; cp.d[i] = dsts[i]; cp.n[i] = ns[i]; }

    dim3 blk(512);
    JobH nj{nullptr, nullptr, nullptr, nullptr, nullptr, nullptr};

    // 0. convert weights/biases to f16
    cvtk<<<dim3(32, 18), 256, 0, stream>>>(cp);
    // 1. x -> chunked f16 Xc
    t_in<<<dim3(16, 4), 256, 0, stream>>>(x, (h8*)hXc);

#define C8(p) ((const h8*)(p))
#define Y8(p) ((h8*)(p))
    // 2. merged min-plus: {Xc,w11 -> M} + {Xc,scw1 -> SC0}
    tsemi<0, 256, 256><<<dim3(16, 48), blk, 0, stream>>>(
        JobH{C8(hXc), w11,  nullptr, nullptr, nullptr, Y8(hM)},
        JobH{C8(hXc), scw1, nullptr, nullptr, nullptr, Y8(hSC0)}, 16);
    // 3. merged max-plus: {M,w12,b12, min Xc -> A} + {SC0,scw2,scb2 -> SCout}
    tsemi<1, 256, 512><<<dim3(16, 48), blk, 0, stream>>>(
        JobH{C8(hM),   w12,  b12,  C8(hXc), nullptr, Y8(hA)},
        JobH{C8(hSC0), scw2, scb2, nullptr, nullptr, Y8(hSCout)}, 16);
    // 4-7. layers 2 and 3
    tsemi<0, 256, 256><<<dim3(16, 16), blk, 0, stream>>>(
        JobH{C8(hA), w21, nullptr, nullptr, nullptr, Y8(hM)}, nj, 16);
    tsemi<1, 256, 256><<<dim3(16, 16), blk, 0, stream>>>(
        JobH{C8(hM), w22, b22, C8(hA), nullptr, Y8(hX2)}, nj, 16);
    tsemi<0, 256, 256><<<dim3(16, 16), blk, 0, stream>>>(
        JobH{C8(hX2), w31, nullptr, nullptr, nullptr, Y8(hM)}, nj, 16);
    tsemi<1, 256, 256><<<dim3(16, 16), blk, 0, stream>>>(
        JobH{C8(hM), w32, b32, C8(hX2), nullptr, Y8(hA)}, nj, 16);   // A = x3
    // 8. merged layer-4 min-plus: {A,w41 -> T} + {A,sw1 -> T2}
    tsemi<0, 256, 256><<<dim3(16, 64), blk, 0, stream>>>(
        JobH{C8(hA), w41, nullptr, nullptr, nullptr, Y8(hT)},
        JobH{C8(hA), sw1, nullptr, nullptr, nullptr, Y8(hT2)}, 32);
    // 9. layer-4 main max-plus -> O4 (staged in d_out)
    tsemi<1, 512, 512><<<dim3(16, 32), blk, 0, stream>>>(
        JobH{C8(hT), w42, b42, nullptr, nullptr, Y8(hO4)}, nj, 32);
    // 10. layer-4 shortcut max-plus, min O4, max SCout -> Zf
    tsemi<1, 512, 512><<<dim3(16, 32), blk, 0, stream>>>(
        JobH{C8(hT2), sw2, sb2, C8(hO4), C8(hSCout), Y8(hZf)}, nj, 32);
    // 11. un-transpose Zf -> out (f32)
    t_out<<<dim3(8, 16), 256, 0, stream>>>(C8(hZf), out);
#undef C8
#undef Y8
}

// Round 11
// 106.139 us; speedup vs baseline: 3.9789x; 1.1497x over previous
//
#include <hip/hip_runtime.h>
#include <math.h>

// Tropical bottleneck network — packed-f16, TLP-geared geometry.
// Activations chunked-transposed [K/8][1024][8] halfs; lane = batch b.
// W (f16, converted once) staged to LDS per block, read broadcast.
// tsemi: 256 threads = 4 waves = 4-way K-split; block = 4 rows x 64 batch.
// Small stages: 1024 blocks (~4-5/CU -> 16+ waves/CU); K=512 stages: 2048.

#define BALL 1024

typedef _Float16 h2 __attribute__((ext_vector_type(2)));
typedef _Float16 h4 __attribute__((ext_vector_type(4)));
typedef _Float16 h8 __attribute__((ext_vector_type(8)));

template<int M, typename V> __device__ __forceinline__ V rdv(V a, V b) {
    if constexpr (M) return __builtin_elementwise_max(a, b);
    else             return __builtin_elementwise_min(a, b);
}
template<int M> __device__ __forceinline__ _Float16 rd1(_Float16 a, _Float16 b) {
    if constexpr (M) return a > b ? a : b;
    else             return a < b ? a : b;
}
template<int M> __device__ __forceinline__ h2 red82(h8 v) {
    h4 lo = __builtin_shufflevector(v, v, 0, 1, 2, 3);
    h4 hi = __builtin_shufflevector(v, v, 4, 5, 6, 7);
    h4 m  = rdv<M>(lo, hi);
    h2 a  = __builtin_shufflevector(m, m, 0, 1);
    h2 b  = __builtin_shufflevector(m, m, 2, 3);
    return rdv<M>(a, b);
}

struct JobH {
    const h8*       X;    // chunked [K/8][1024]
    const _Float16* W;    // [rows][K] row-major
    const _Float16* bias; // [rows] (max stages)
    const h4*       E1;   // chunked min-combine or nullptr
    const h4*       E2;   // chunked max-combine or nullptr
    h4*             Y;    // chunked [rows/8][1024][2]
};

template<int ISMAX, int K>
__device__ __forceinline__ void run_jobH(
    const JobH j, int by, h8* __restrict__ Wl,
    h2 (* __restrict__ part)[4][64])
{
    const int tid  = threadIdx.x;       // 0..255
    const int lane = tid & 63;
    const int q    = tid >> 6;          // K-quarter 0..3
    const int b    = blockIdx.x * 64 + lane;
    const int i0   = by * 4;            // 4 rows per block

    // stage W[4 rows][K halfs] into LDS: K/2 h8 elements, 1 load/thread max
    const h8* Wg = (const h8*)(j.W + (size_t)i0 * K);
    if (tid < K / 2) Wl[tid] = Wg[tid];
    __syncthreads();

    constexpr int CQ = K / 32;          // chunks per quarter (8 or 16)
    const int kcB = q * CQ;
    const h8* Xb = j.X + b;
    const h8* Wr = Wl;                  // 4 rows x K/8 chunks

    h8 acc[4];
    {   // peel first chunk: init = x + w (no +-INF)
        h8 xv = Xb[(size_t)kcB * BALL];
#pragma unroll
        for (int r = 0; r < 4; ++r) acc[r] = xv + Wr[r * (K / 8) + kcB];
    }
#pragma unroll 4
    for (int kc = kcB + 1; kc < kcB + CQ; ++kc) {
        h8 xv = Xb[(size_t)kc * BALL];
#pragma unroll
        for (int r = 0; r < 4; ++r)
            acc[r] = rdv<ISMAX>(acc[r], xv + Wr[r * (K / 8) + kc]);
    }

    if (q) {
#pragma unroll
        for (int r = 0; r < 4; ++r)
            part[q - 1][r][lane] = red82<ISMAX>(acc[r]);
    }
    __syncthreads();
    if (q == 0) {
        h4 o;
#pragma unroll
        for (int r = 0; r < 4; ++r) {
            h2 m = red82<ISMAX>(acc[r]);
#pragma unroll
            for (int qq = 0; qq < 3; ++qq)
                m = rdv<ISMAX>(m, part[qq][r][lane]);
            o[r] = rd1<ISMAX>(m[0], m[1]);
        }
        // output: h4 = half a chunk. chunk c0 = i0>>3, half = (i0>>2)&1
        const size_t idx = ((size_t)(i0 >> 3) * BALL + b) * 2 + ((i0 >> 2) & 1);
        if (ISMAX) o = o + *(const h4*)(j.bias + i0);
        if (j.E1)  o = __builtin_elementwise_min(o, j.E1[idx]);
        if (j.E2)  o = __builtin_elementwise_max(o, j.E2[idx]);
        j.Y[idx] = o;
    }
}

// Two jobs per launch: blocks with blockIdx.y < nbyA run ja (K=KA), rest jb (K=KB).
template<int ISMAX, int KA, int KB>
__global__ __launch_bounds__(256) void tsemi(JobH ja, JobH jb, int nbyA)
{
    constexpr int KM = (KA > KB) ? KA : KB;
    __shared__ __align__(16) h8 Wl[KM / 2];      // 4 rows x K halfs
    __shared__ h2 part[3][4][64];
    const int by = blockIdx.y;
    if (by < nbyA) run_jobH<ISMAX, KA>(ja, by, Wl, part);
    else           run_jobH<ISMAX, KB>(jb, by - nbyA, Wl, part);
}

// weight/bias f32 -> f16 conversion: 18 segments
struct CvtP {
    const float* s[18];
    _Float16*    d[18];
    int          n[18];
};
__global__ __launch_bounds__(256) void cvtk(CvtP p)
{
    const int seg = blockIdx.y;
    const float2* s2 = (const float2*)p.s[seg];
    h2*           d2 = (h2*)p.d[seg];
    const int n2 = p.n[seg] >> 1;
    for (int i = blockIdx.x * 256 + threadIdx.x; i < n2; i += gridDim.x * 256) {
        float2 v = s2[i];
        h2 o; o[0] = (_Float16)v.x; o[1] = (_Float16)v.y;
        d2[i] = o;
    }
}

// x f32 [1024][256] -> Xc f16 chunked [32][1024][8]
__global__ __launch_bounds__(256) void t_in(const float* __restrict__ x,
                                            h8* __restrict__ Xc)
{
    __shared__ float s[64][65];
    const int lane = threadIdx.x & 63;
    const int ty   = threadIdx.x >> 6;
    const int b0   = blockIdx.x * 64;
    const int k0   = blockIdx.y * 64;
#pragma unroll
    for (int r = ty; r < 64; r += 4)
        s[r][lane] = x[(size_t)(b0 + r) * 256 + k0 + lane];
    __syncthreads();
#pragma unroll
    for (int cc = 0; cc < 2; ++cc) {
        int c = ty * 2 + cc;            // chunk within tile, 0..7
        h8 v;
#pragma unroll
        for (int jj = 0; jj < 8; ++jj) v[jj] = (_Float16)s[lane][c * 8 + jj];
        Xc[(size_t)(k0 / 8 + c) * BALL + b0 + lane] = v;
    }
}

// Zf f16 chunked [64][1024][8] -> out f32 [1024][512]
__global__ __launch_bounds__(256) void t_out(const h8* __restrict__ Zc,
                                             float* __restrict__ out)
{
    __shared__ float s[64][65];
    const int lane = threadIdx.x & 63;
    const int ty   = threadIdx.x >> 6;
    const int i0   = blockIdx.x * 64;
    const int b0   = blockIdx.y * 64;
#pragma unroll
    for (int cc = 0; cc < 2; ++cc) {
        int c = ty * 2 + cc;            // row-chunk within tile, 0..7
        h8 v = Zc[(size_t)(i0 / 8 + c) * BALL + b0 + lane];
#pragma unroll
        for (int jj = 0; jj < 8; ++jj) s[lane][c * 8 + jj] = (float)v[jj];
    }
    __syncthreads();
#pragma unroll
    for (int r = ty; r < 64; r += 4)
        out[(size_t)(b0 + r) * 512 + i0 + lane] = s[r][lane];
}

extern "C" void kernel_launch(void* const* d_in, const int* in_sizes, int n_in,
                              void* d_out, int out_size, void* d_ws, size_t ws_size,
                              hipStream_t stream) {
    (void)in_sizes; (void)n_in; (void)ws_size; (void)out_size;
    const float* fin[19];
    for (int i = 0; i < 19; ++i) fin[i] = (const float*)d_in[i];
    const float* x = fin[0];

    float*     out = (float*)d_out;
    _Float16*  hw  = (_Float16*)d_ws;

    // half-unit workspace layout (~6.76 MB, proven in R10):
    _Float16* hXc    = hw;                 // 262144 halfs (x chunked; X2 alias)
    _Float16* hM     = hw + 262144;
    _Float16* hA     = hw + 524288;
    _Float16* hSC0   = hw + 786432;        // 524288 halfs
    _Float16* hSCout = hw + 1310720;       // 524288 halfs
    _Float16* hW     = hw + 1835008;       // converted weights+biases
    // lifetime-disjoint aliases:
    _Float16* hX2 = hXc;
    _Float16* hT  = hSC0;
    _Float16* hT2 = hXc;
    _Float16* hZf = hSC0;
    _Float16* hO4 = (_Float16*)d_out;      // d_out doubles as f16 chunked scratch

    _Float16* w11  = hW;            _Float16* w12  = hW + 65536;
    _Float16* w21  = hW + 131072;   _Float16* w22  = hW + 196608;
    _Float16* w31  = hW + 262144;   _Float16* w32  = hW + 327680;
    _Float16* w41  = hW + 393216;   _Float16* w42  = hW + 524288;
    _Float16* sw1  = hW + 786432;   _Float16* sw2  = hW + 917504;
    _Float16* scw1 = hW + 1179648;  _Float16* scw2 = hW + 1441792;
    _Float16* b12  = hW + 1703936;  _Float16* b22  = hW + 1704192;
    _Float16* b32  = hW + 1704448;  _Float16* b42  = hW + 1704704;
    _Float16* sb2  = hW + 1705216;  _Float16* scb2 = hW + 1705728;

    CvtP cp;
    const int srcIdx[18] = {1,2,4,5,7,8, 10,11,13,14,16,17, 3,6,9,12,15,18};
    _Float16* dsts[18]   = {w11,w12,w21,w22,w31,w32, w41,w42,sw1,sw2,scw1,scw2,
                            b12,b22,b32,b42,sb2,scb2};
    const int ns[18]     = {65536,65536,65536,65536,65536,65536,
                            131072,262144,131072,262144,131072,262144,
                            256,256,256,512,512,512};
    for (int i = 0; i < 18; ++i) { cp.s[i] = fin[srcIdx[i]]; cp.d[i] = dsts[i]; cp.n[i] = ns[i]; }

    dim3 blk(256);
    JobH nj{nullptr, nullptr, nullptr, nullptr, nullptr, nullptr};

    // 0. convert weights/biases to f16
    cvtk<<<dim3(32, 18), 256, 0, stream>>>(cp);
    // 1. x -> chunked f16 Xc
    t_in<<<dim3(16, 4), 256, 0, stream>>>(x, (h8*)hXc);

#define C8(p) ((const h8*)(p))
#define C4(p) ((const h4*)(p))
#define Y4(p) ((h4*)(p))
    // 2. merged min-plus: {Xc,w11 -> M (256r)} + {Xc,scw1 -> SC0 (512r)}
    tsemi<0, 256, 256><<<dim3(16, 192), blk, 0, stream>>>(
        JobH{C8(hXc), w11,  nullptr, nullptr, nullptr, Y4(hM)},
        JobH{C8(hXc), scw1, nullptr, nullptr, nullptr, Y4(hSC0)}, 64);
    // 3. merged max-plus: {M,w12,b12, min Xc -> A} + {SC0,scw2,scb2 -> SCout}
    tsemi<1, 256, 512><<<dim3(16, 192), blk, 0, stream>>>(
        JobH{C8(hM),   w12,  b12,  C4(hXc), nullptr, Y4(hA)},
        JobH{C8(hSC0), scw2, scb2, nullptr, nullptr, Y4(hSCout)}, 64);
    // 4-7. layers 2 and 3 (single job)
    tsemi<0, 256, 256><<<dim3(16, 64), blk, 0, stream>>>(
        JobH{C8(hA), w21, nullptr, nullptr, nullptr, Y4(hM)}, nj, 64);
    tsemi<1, 256, 256><<<dim3(16, 64), blk, 0, stream>>>(
        JobH{C8(hM), w22, b22, C4(hA), nullptr, Y4(hX2)}, nj, 64);
    tsemi<0, 256, 256><<<dim3(16, 64), blk, 0, stream>>>(
        JobH{C8(hX2), w31, nullptr, nullptr, nullptr, Y4(hM)}, nj, 64);
    tsemi<1, 256, 256><<<dim3(16, 64), blk, 0, stream>>>(
        JobH{C8(hM), w32, b32, C4(hX2), nullptr, Y4(hA)}, nj, 64);   // A = x3
    // 8. merged layer-4 min-plus: {A,w41 -> T} + {A,sw1 -> T2} (512r each)
    tsemi<0, 256, 256><<<dim3(16, 256), blk, 0, stream>>>(
        JobH{C8(hA), w41, nullptr, nullptr, nullptr, Y4(hT)},
        JobH{C8(hA), sw1, nullptr, nullptr, nullptr, Y4(hT2)}, 128);
    // 9. layer-4 main max-plus -> O4 (staged in d_out)
    tsemi<1, 512, 512><<<dim3(16, 128), blk, 0, stream>>>(
        JobH{C8(hT), w42, b42, nullptr, nullptr, Y4(hO4)}, nj, 128);
    // 10. layer-4 shortcut max-plus, min O4, max SCout -> Zf
    tsemi<1, 512, 512><<<dim3(16, 128), blk, 0, stream>>>(
        JobH{C8(hT2), sw2, sb2, C4(hO4), C4(hSCout), Y4(hZf)}, nj, 128);
    // 11. un-transpose Zf -> out (f32)
    t_out<<<dim3(8, 16), 256, 0, stream>>>(C8(hZf), out);
#undef C8
#undef C4
#undef Y4
}

// Round 12
// 100.294 us; speedup vs baseline: 4.2108x; 1.0583x over previous
//
#include <hip/hip_runtime.h>
#include <math.h>

// Tropical bottleneck network — FULLY FUSED single kernel (per-batch-slice),
// packed f16. Batch rows never mix, so each block owns 4 batch columns and
// runs all 12 stages locally with only __syncthreads() between stages.
// Activations live in LDS ([k][4b] f16). Weights are pre-converted to f16 and
// pre-chunked Wc[K/8][R][8] (one-time cvt kernels) and streamed from L2 —
// all 256 blocks read the same 3.1 MB, L2-resident.
// Per stage: lane = output row (W loads coalesced 16B/lane), x broadcast from
// LDS, 2 rows/thread, K-split (4-way for R=256, 2-way for R=512) + LDS combine.

typedef _Float16 h2 __attribute__((ext_vector_type(2)));
typedef _Float16 h8 __attribute__((ext_vector_type(8)));

template<int M> __device__ __forceinline__ h2 rdv(h2 a, h2 b) {
    if constexpr (M) return __builtin_elementwise_max(a, b);
    else             return __builtin_elementwise_min(a, b);
}

struct NetP {
    const float* x;
    const h8 *w11, *w12, *w21, *w22, *w31, *w32;
    const h8 *w41, *w42, *sw1, *sw2, *scw1, *scw2;
    const _Float16 *b12, *b22, *b32, *b42, *sb2, *scb2;
    float* out;
};

// One semiring stage on this block's 4 batch cols.
// X: LDS [K][4] halfs. Y: LDS [R][4] (or global f32 out if GOUT).
template<int ISMAX, int R, int K, int KS, bool GOUT>
__device__ __forceinline__ void stage(
    const h8* __restrict__ Wc,          // global chunked [K/8][R]
    const _Float16* __restrict__ bias,  // global f16 (ISMAX) or nullptr
    const _Float16* __restrict__ X,
    const _Float16* __restrict__ E1,    // LDS min-combine or nullptr
    const _Float16* __restrict__ E2,    // LDS max-combine or nullptr
    _Float16* __restrict__ Y,
    float* __restrict__ gout, int b0,
    h2* __restrict__ part)
{
    constexpr int NRG = R / 2;               // row-groups
    static_assert(NRG * KS == 512, "thread mapping");
    const int tid  = threadIdx.x;
    const int rowg = tid & (NRG - 1);
    const int kq   = tid / NRG;
    const int r0 = rowg, r1 = rowg + NRG;
    constexpr int NC = (K / KS) / 8;         // chunks per thread
    const int kc0 = kq * NC;

    const h2* Xh2 = (const h2*)X;

    h2 a00, a01, a10, a11;
    {   // peel first chunk (init, no +-INF)
        h8 w0 = Wc[(size_t)kc0 * R + r0];
        h8 w1 = Wc[(size_t)kc0 * R + r1];
        const h2* xk = Xh2 + kc0 * 16;
        h2 xs0 = xk[0], xs1 = xk[1];
        h2 u = {w0[0], w0[0]}, v = {w1[0], w1[0]};
        a00 = xs0 + u; a01 = xs1 + u;
        a10 = xs0 + v; a11 = xs1 + v;
#pragma unroll
        for (int j = 1; j < 8; ++j) {
            xs0 = xk[2 * j]; xs1 = xk[2 * j + 1];
            h2 uu = {w0[j], w0[j]}, vv = {w1[j], w1[j]};
            a00 = rdv<ISMAX>(a00, xs0 + uu); a01 = rdv<ISMAX>(a01, xs1 + uu);
            a10 = rdv<ISMAX>(a10, xs0 + vv); a11 = rdv<ISMAX>(a11, xs1 + vv);
        }
    }
#pragma unroll 2
    for (int kc = kc0 + 1; kc < kc0 + NC; ++kc) {
        h8 w0 = Wc[(size_t)kc * R + r0];
        h8 w1 = Wc[(size_t)kc * R + r1];
        const h2* xk = Xh2 + kc * 16;
#pragma unroll
        for (int j = 0; j < 8; ++j) {
            h2 xs0 = xk[2 * j], xs1 = xk[2 * j + 1];
            h2 uu = {w0[j], w0[j]}, vv = {w1[j], w1[j]};
            a00 = rdv<ISMAX>(a00, xs0 + uu); a01 = rdv<ISMAX>(a01, xs1 + uu);
            a10 = rdv<ISMAX>(a10, xs0 + vv); a11 = rdv<ISMAX>(a11, xs1 + vv);
        }
    }

    if (kq) {
        h2* pp = part + (size_t)(kq - 1) * R * 2;
        pp[r0 * 2] = a00; pp[r0 * 2 + 1] = a01;
        pp[r1 * 2] = a10; pp[r1 * 2 + 1] = a11;
    }
    __syncthreads();
    if (kq == 0) {
#pragma unroll
        for (int qq = 0; qq < KS - 1; ++qq) {
            const h2* pp = part + (size_t)qq * R * 2;
            a00 = rdv<ISMAX>(a00, pp[r0 * 2]); a01 = rdv<ISMAX>(a01, pp[r0 * 2 + 1]);
            a10 = rdv<ISMAX>(a10, pp[r1 * 2]); a11 = rdv<ISMAX>(a11, pp[r1 * 2 + 1]);
        }
        if (ISMAX) {
            _Float16 q0 = bias[r0], q1 = bias[r1];
            h2 s0 = {q0, q0}, s1 = {q1, q1};
            a00 += s0; a01 += s0; a10 += s1; a11 += s1;
        }
        if (E1) {
            const h2* e = (const h2*)E1;
            a00 = __builtin_elementwise_min(a00, e[r0 * 2]);
            a01 = __builtin_elementwise_min(a01, e[r0 * 2 + 1]);
            a10 = __builtin_elementwise_min(a10, e[r1 * 2]);
            a11 = __builtin_elementwise_min(a11, e[r1 * 2 + 1]);
        }
        if (E2) {
            const h2* e = (const h2*)E2;
            a00 = __builtin_elementwise_max(a00, e[r0 * 2]);
            a01 = __builtin_elementwise_max(a01, e[r0 * 2 + 1]);
            a10 = __builtin_elementwise_max(a10, e[r1 * 2]);
            a11 = __builtin_elementwise_max(a11, e[r1 * 2 + 1]);
        }
        if constexpr (GOUT) {
            gout[(size_t)(b0 + 0) * 512 + r0] = (float)a00[0];
            gout[(size_t)(b0 + 1) * 512 + r0] = (float)a00[1];
            gout[(size_t)(b0 + 2) * 512 + r0] = (float)a01[0];
            gout[(size_t)(b0 + 3) * 512 + r0] = (float)a01[1];
            gout[(size_t)(b0 + 0) * 512 + r1] = (float)a10[0];
            gout[(size_t)(b0 + 1) * 512 + r1] = (float)a10[1];
            gout[(size_t)(b0 + 2) * 512 + r1] = (float)a11[0];
            gout[(size_t)(b0 + 3) * 512 + r1] = (float)a11[1];
        } else {
            h2* y = (h2*)Y;
            y[r0 * 2] = a00; y[r0 * 2 + 1] = a01;
            y[r1 * 2] = a10; y[r1 * 2 + 1] = a11;
        }
    }
    __syncthreads();
}

__global__ __launch_bounds__(512) void netf(NetP p)
{
    __shared__ _Float16 X0[256 * 4];               // 2 KB
    __shared__ _Float16 B0[512 * 4], B1[512 * 4];  // 4 KB each
    __shared__ _Float16 B2[512 * 4], B3[512 * 4];
    __shared__ h2 part[1536];                      // 6 KB
    const int tid = threadIdx.x;
    const int b0  = blockIdx.x * 4;

    {   // load x f32 -> X0 f16 [k][4b]
        const int bl = tid >> 7;          // 0..3
        const int k2 = tid & 127;         // pair of k's
        float2 v = *(const float2*)&p.x[(size_t)(b0 + bl) * 256 + k2 * 2];
        X0[(k2 * 2 + 0) * 4 + bl] = (_Float16)v.x;
        X0[(k2 * 2 + 1) * 4 + bl] = (_Float16)v.y;
    }
    __syncthreads();

    float* o = p.out;
    // bottleneck shortcut first (keeps X0 live only through stage 4)
    stage<0,512,256,2,false>(p.scw1, nullptr, X0, nullptr, nullptr, B0, o, b0, part);
    stage<1,512,512,2,false>(p.scw2, p.scb2, B0, nullptr, nullptr, B1, o, b0, part); // B1=SCout
    // layer 1
    stage<0,256,256,4,false>(p.w11, nullptr, X0, nullptr, nullptr, B0, o, b0, part);
    stage<1,256,256,4,false>(p.w12, p.b12, B0, X0, nullptr, B2, o, b0, part);
    // layer 2
    stage<0,256,256,4,false>(p.w21, nullptr, B2, nullptr, nullptr, B0, o, b0, part);
    stage<1,256,256,4,false>(p.w22, p.b22, B0, B2, nullptr, B3, o, b0, part);
    // layer 3
    stage<0,256,256,4,false>(p.w31, nullptr, B3, nullptr, nullptr, B0, o, b0, part);
    stage<1,256,256,4,false>(p.w32, p.b32, B0, B3, nullptr, B2, o, b0, part);        // B2=x3
    // layer 4
    stage<0,512,256,2,false>(p.w41, nullptr, B2, nullptr, nullptr, B0, o, b0, part); // T1
    stage<0,512,256,2,false>(p.sw1, nullptr, B2, nullptr, nullptr, B3, o, b0, part); // T2
    stage<1,512,512,2,false>(p.w42, p.b42, B0, nullptr, nullptr, B2, o, b0, part);   // O4=B2
    // final: max(min(maxbplus(T2,sw2,sb2), O4), SCout) -> global out
    stage<1,512,512,2,true >(p.sw2, p.sb2, B3, B2, B1, nullptr, o, b0, part);
}

// ---- one-time weight prep: f32 [R][K] -> f16 chunked Wc[K/8][R][8] ----
struct CW { const float* s[12]; h8* d[12]; int R[12]; int K[12]; };
__global__ __launch_bounds__(256) void cvtw(CW p)
{
    const int m = blockIdx.y;
    const int R = p.R[m], K = p.K[m];
    const int tilesR = R >> 6;
    const int nt = tilesR * (K >> 6);
    const int t = blockIdx.x;
    if (t >= nt) return;
    const int tr = t % tilesR, tk = t / tilesR;

    __shared__ float s[64][65];
    const int lane = threadIdx.x & 63, ty = threadIdx.x >> 6;
    const float* src = p.s[m];
#pragma unroll
    for (int r = ty; r < 64; r += 4)
        s[r][lane] = src[(size_t)(tr * 64 + r) * K + tk * 64 + lane];
    __syncthreads();
    h8* dst = p.d[m];
#pragma unroll
    for (int c = 0; c < 2; ++c) {
        int cc = ty + c * 4;                 // 0..7
        h8 v;
#pragma unroll
        for (int j = 0; j < 8; ++j) v[j] = (_Float16)s[lane][cc * 8 + j];
        dst[(size_t)(tk * 8 + cc) * R + tr * 64 + lane] = v;
    }
}

struct CB { const float* s[6]; _Float16* d[6]; int n[6]; };
__global__ __launch_bounds__(256) void cvtb(CB p)
{
    for (int m = 0; m < 6; ++m)
        for (int i = threadIdx.x; i < p.n[m]; i += 256)
            p.d[m][i] = (_Float16)p.s[m][i];
}

extern "C" void kernel_launch(void* const* d_in, const int* in_sizes, int n_in,
                              void* d_out, int out_size, void* d_ws, size_t ws_size,
                              hipStream_t stream) {
    (void)in_sizes; (void)n_in; (void)ws_size; (void)out_size;
    const float* fin[19];
    for (int i = 0; i < 19; ++i) fin[i] = (const float*)d_in[i];

    _Float16* hw = (_Float16*)d_ws;

    // chunked f16 weights in ws (halfs); all offsets multiples of 8 (16B align)
    // sizes: (256,256)->65536 ; (512,256)->131072 ; (512,512)->262144
    _Float16* w11c  = hw;
    _Float16* w12c  = hw + 65536;
    _Float16* w21c  = hw + 131072;
    _Float16* w22c  = hw + 196608;
    _Float16* w31c  = hw + 262144;
    _Float16* w32c  = hw + 327680;
    _Float16* w41c  = hw + 393216;   // 131072
    _Float16* w42c  = hw + 524288;   // 262144
    _Float16* sw1c  = hw + 786432;   // 131072
    _Float16* sw2c  = hw + 917504;   // 262144
    _Float16* scw1c = hw + 1179648;  // 131072
    _Float16* scw2c = hw + 1310720;  // 262144
    _Float16* bia   = hw + 1572864;  // biases: 256*3 + 512*3 = 2304
    _Float16* b12 = bia, *b22 = bia + 256, *b32 = bia + 512;
    _Float16* b42 = bia + 768, *sb2 = bia + 1280, *scb2 = bia + 1792;

    CW cw;
    const float* wsrc[12] = {fin[1], fin[2], fin[4], fin[5], fin[7], fin[8],
                             fin[10], fin[11], fin[13], fin[14], fin[16], fin[17]};
    _Float16* wdst[12]    = {w11c, w12c, w21c, w22c, w31c, w32c,
                             w41c, w42c, sw1c, sw2c, scw1c, scw2c};
    const int wR[12] = {256,256,256,256,256,256, 512,512,512,512,512,512};
    const int wK[12] = {256,256,256,256,256,256, 256,512,256,512,256,512};
    for (int i = 0; i < 12; ++i) {
        cw.s[i] = wsrc[i]; cw.d[i] = (h8*)wdst[i]; cw.R[i] = wR[i]; cw.K[i] = wK[i];
    }
    CB cb;
    const float* bsrc[6] = {fin[3], fin[6], fin[9], fin[12], fin[15], fin[18]};
    _Float16* bdst[6]    = {b12, b22, b32, b42, sb2, scb2};
    const int bn[6]      = {256, 256, 256, 512, 512, 512};
    for (int i = 0; i < 6; ++i) { cb.s[i] = bsrc[i]; cb.d[i] = bdst[i]; cb.n[i] = bn[i]; }

    NetP p;
    p.x   = fin[0];
    p.w11 = (const h8*)w11c; p.w12 = (const h8*)w12c;
    p.w21 = (const h8*)w21c; p.w22 = (const h8*)w22c;
    p.w31 = (const h8*)w31c; p.w32 = (const h8*)w32c;
    p.w41 = (const h8*)w41c; p.w42 = (const h8*)w42c;
    p.sw1 = (const h8*)sw1c; p.sw2 = (const h8*)sw2c;
    p.scw1 = (const h8*)scw1c; p.scw2 = (const h8*)scw2c;
    p.b12 = b12; p.b22 = b22; p.b32 = b32; p.b42 = b42; p.sb2 = sb2; p.scb2 = scb2;
    p.out = (float*)d_out;

    cvtw<<<dim3(64, 12), 256, 0, stream>>>(cw);
    cvtb<<<1, 256, 0, stream>>>(cb);
    netf<<<dim3(256), 512, 0, stream>>>(p);
}